// Round 1
// baseline (1285.160 us; speedup 1.0000x reference)
//
#include <hip/hip_runtime.h>
#include <cstdint>
#include <cstddef>

// Dims (fixed by the problem)
#define BB 8
#define CC 128
#define C3 384
#define HH 64
#define H2 32
#define NPIX 1024   // 32*32
#define N4 4096     // 64*64
#define NHD 8
#define HD 16

// ---------------- K1: Haar DWT ----------------
// x (8,128,64,64) -> ll (8,128,1024), high (8,384,1024) [lh | hl | hh]
__global__ __launch_bounds__(256) void k_dwt(const float* __restrict__ x,
                                             float* __restrict__ ll,
                                             float* __restrict__ high) {
  int idx = blockIdx.x * 256 + threadIdx.x;   // B*C*32*32 = 1,048,576
  int w = idx & 31, h = (idx >> 5) & 31, c = (idx >> 10) & 127, b = idx >> 17;
  const float* xp = x + ((size_t)(b * CC + c) * HH + 2 * h) * HH + 2 * w;
  float x1 = xp[0];        // even row, even col
  float x2 = xp[HH];       // odd row,  even col
  float x3 = xp[1];        // even row, odd col
  float x4 = xp[HH + 1];   // odd row,  odd col
  int n = h * H2 + w;
  ll[(size_t)(b * CC + c) * NPIX + n]              = 0.5f * ( x1 + x2 + x3 + x4);
  high[((size_t)b * C3 + c) * NPIX + n]            = 0.5f * (-x1 - x2 + x3 + x4);
  high[((size_t)b * C3 + CC + c) * NPIX + n]       = 0.5f * (-x1 + x2 - x3 + x4);
  high[((size_t)b * C3 + 2 * CC + c) * NPIX + n]   = 0.5f * ( x1 - x2 - x3 + x4);
}

// ---------------- Generic conv1x1 (GEMM) ----------------
// out[b,o,n] = sum_c w[o,c] * in[b,c,n].  Block: 256 pixels, 16 output chans.
// grid = (Npix/256, Cout/16, B)
template <int CIN>
__global__ __launch_bounds__(256) void k_conv1x1(const float* __restrict__ in,
                                                 const float* __restrict__ w,
                                                 float* __restrict__ out,
                                                 int Cout, int Npix) {
  __shared__ float lds[32 * 256];
  int tid = threadIdx.x;
  int n = blockIdx.x * 256 + tid;
  int o0 = blockIdx.y * 16;
  int b = blockIdx.z;
  const float* inb = in + (size_t)b * CIN * Npix + n;
  float acc[16];
#pragma unroll
  for (int o = 0; o < 16; ++o) acc[o] = 0.f;
  for (int c0 = 0; c0 < CIN; c0 += 32) {
    __syncthreads();
#pragma unroll
    for (int c = 0; c < 32; ++c) lds[c * 256 + tid] = inb[(size_t)(c0 + c) * Npix];
    __syncthreads();
#pragma unroll
    for (int c = 0; c < 32; ++c) {
      float vv = lds[c * 256 + tid];
#pragma unroll
      for (int o = 0; o < 16; ++o)
        acc[o] = fmaf(w[(size_t)(o0 + o) * CIN + c0 + c], vv, acc[o]);
    }
  }
  size_t ob = ((size_t)b * Cout + o0) * Npix + n;
#pragma unroll
  for (int o = 0; o < 16; ++o) out[ob + (size_t)o * Npix] = acc[o];
}

// ---------------- K2b: split qkv + l2norm q,k ----------------
// qkv (b, 3*128, n) -> qn/kn/v in (b,h,n,d) row-major (d contiguous)
__global__ __launch_bounds__(256) void k_qkvnorm(const float* __restrict__ qkv,
                                                 float* __restrict__ qn,
                                                 float* __restrict__ kn,
                                                 float* __restrict__ vout) {
  int idx = blockIdx.x * 256 + threadIdx.x;  // 65536 = B*NH*NPIX
  int n = idx & 1023, h = (idx >> 10) & 7, b = idx >> 13;
  const float* base = qkv + ((size_t)b * C3 + h * HD) * NPIX + n;
  float q[HD], k[HD], vv[HD];
  float sq = 0.f, sk = 0.f;
#pragma unroll
  for (int d = 0; d < HD; ++d) {
    q[d] = base[(size_t)d * NPIX];
    k[d] = base[(size_t)(CC + d) * NPIX];
    vv[d] = base[(size_t)(2 * CC + d) * NPIX];
    sq += q[d] * q[d];
    sk += k[d] * k[d];
  }
  float rq = 1.f / fmaxf(sqrtf(sq), 1e-12f);
  float rk = 1.f / fmaxf(sqrtf(sk), 1e-12f);
  float* qo = qn + (size_t)idx * HD;
  float* ko = kn + (size_t)idx * HD;
  float* vo = vout + (size_t)idx * HD;
#pragma unroll
  for (int d = 0; d < HD; ++d) { qo[d] = q[d] * rq; ko[d] = k[d] * rk; vo[d] = vv[d]; }
}

// ---------------- K3: sparse top-k attention, one wave per query row ----------------
__global__ __launch_bounds__(256) void k_attn(const float* __restrict__ qn,
                                              const float* __restrict__ kn,
                                              const float* __restrict__ v,
                                              float* __restrict__ attn_out) {
  int lane = threadIdx.x & 63;
  int row = blockIdx.x * 4 + (threadIdx.x >> 6);  // 0..65535 == (b*8+h)*1024+n
  int n = row & 1023;
  int bh = row >> 10;
  const float* qrow = qn + (size_t)row * HD;
  float q[HD];
#pragma unroll
  for (int d = 0; d < HD; d += 4) {
    float4 t = *(const float4*)(qrow + d);
    q[d] = t.x; q[d + 1] = t.y; q[d + 2] = t.z; q[d + 3] = t.w;
  }
  const float* kb = kn + (size_t)bh * NPIX * HD;
  const float* vb = v + (size_t)bh * NPIX * HD;
  float s[16];
#pragma unroll
  for (int i = 0; i < 16; ++i) {
    const float* kr = kb + (size_t)(i * 64 + lane) * HD;
    float acc = 0.f;
#pragma unroll
    for (int d = 0; d < HD; d += 4) {
      float4 t = *(const float4*)(kr + d);
      acc += q[d] * t.x + q[d + 1] * t.y + q[d + 2] * t.z + q[d + 3] * t.w;
    }
    acc *= 0.25f;                                  // hd^-0.5
    s[i] = fminf(fmaxf(acc, -32.f), 32.f);         // clip
  }
  // row max/min via wave reduce
  float mx = -1e30f, mn = 1e30f;
#pragma unroll
  for (int i = 0; i < 16; ++i) { mx = fmaxf(mx, s[i]); mn = fminf(mn, s[i]); }
#pragma unroll
  for (int off = 32; off > 0; off >>= 1) {
    mx = fmaxf(mx, __shfl_xor(mx, off));
    mn = fminf(mn, __shfl_xor(mn, off));
  }
  // bisect for the 512th-largest value. invariant: count(>=lo) >= 512
  float lo = mn, hi = mx;
  for (int it = 0; it < 16; ++it) {
    float mid = 0.5f * (lo + hi);
    int cnt = 0;
#pragma unroll
    for (int i = 0; i < 16; ++i) cnt += (s[i] >= mid) ? 1 : 0;
#pragma unroll
    for (int off = 32; off > 0; off >>= 1) cnt += __shfl_xor(cnt, off);
    if (cnt >= 512) lo = mid; else hi = mid;
  }
  float thr = lo;
  // masked softmax
  float p[16];
  float sum = 0.f;
#pragma unroll
  for (int i = 0; i < 16; ++i) {
    p[i] = (s[i] >= thr) ? __expf(s[i] - mx) : 0.f;
    sum += p[i];
  }
#pragma unroll
  for (int off = 32; off > 0; off >>= 1) sum += __shfl_xor(sum, off);
  float inv = 1.f / sum;
  // AV
  float o[HD];
#pragma unroll
  for (int d = 0; d < HD; ++d) o[d] = 0.f;
#pragma unroll
  for (int i = 0; i < 16; ++i) {
    const float* vr = vb + (size_t)(i * 64 + lane) * HD;
    float pj = p[i] * inv;
#pragma unroll
    for (int d = 0; d < HD; d += 4) {
      float4 t = *(const float4*)(vr + d);
      o[d] += pj * t.x; o[d + 1] += pj * t.y; o[d + 2] += pj * t.z; o[d + 3] += pj * t.w;
    }
  }
#pragma unroll
  for (int d = 0; d < HD; ++d) {
    float t2 = o[d];
#pragma unroll
    for (int off = 32; off > 0; off >>= 1) t2 += __shfl_xor(t2, off);
    o[d] = t2;
  }
  int b = bh >> 3, h = bh & 7;
  size_t ob = ((size_t)b * CC + h * HD) * NPIX + n;
#pragma unroll
  for (int d = 0; d < HD; ++d)
    if (lane == d) attn_out[ob + (size_t)d * NPIX] = o[d];
}

// ---------------- K5a: depthwise 3x3 SAME conv ----------------
__global__ __launch_bounds__(256) void k_dwconv(const float* __restrict__ in,
                                                const float* __restrict__ w,
                                                float* __restrict__ out) {
  int n = blockIdx.x * 256 + threadIdx.x;
  int c = blockIdx.y, b = blockIdx.z;
  int i = n >> 5, j = n & 31;
  const float* inb = in + ((size_t)b * C3 + c) * NPIX;
  const float* wc = w + c * 9;
  float acc = 0.f;
#pragma unroll
  for (int di = -1; di <= 1; ++di) {
    int ii = i + di;
    if (ii < 0 || ii > 31) continue;
#pragma unroll
    for (int dj = -1; dj <= 1; ++dj) {
      int jj = j + dj;
      if (jj < 0 || jj > 31) continue;
      acc += inb[ii * 32 + jj] * wc[(di + 1) * 3 + (dj + 1)];
    }
  }
  out[((size_t)b * C3 + c) * NPIX + n] = acc;
}

// ---------------- GroupNorm (32 groups) + fused epilogue ----------------
// ACT: 0 none, 1 silu, 2 exact gelu.  HAS_RES: out = res + a*gn (ACT must be 0).
// grid = B*32 blocks; each group is a contiguous chPerGroup*Npix slab.
template <int ACT, bool HAS_RES>
__global__ __launch_bounds__(256) void k_gn(const float* __restrict__ x,
                                            const float* __restrict__ res,
                                            float* __restrict__ out,
                                            const float* __restrict__ gamma,
                                            const float* __restrict__ beta,
                                            const float* __restrict__ alpha_ptr,
                                            float alpha_const,
                                            int chPerGroup, int Npix, int nshift) {
  int g = blockIdx.x & 31, b = blockIdx.x >> 5;
  int Cout = 32 * chPerGroup;
  int elems = chPerGroup * Npix;
  size_t base = ((size_t)b * Cout + g * chPerGroup) * Npix;
  int tid = threadIdx.x;
  float s = 0.f, s2 = 0.f;
  for (int i = tid; i < elems; i += 256) {
    float v = x[base + i];
    s += v; s2 += v * v;
  }
  __shared__ float ls[256], ls2[256];
  ls[tid] = s; ls2[tid] = s2;
  __syncthreads();
  for (int st = 128; st > 0; st >>= 1) {
    if (tid < st) { ls[tid] += ls[tid + st]; ls2[tid] += ls2[tid + st]; }
    __syncthreads();
  }
  float inv_n = 1.f / (float)elems;
  float mean = ls[0] * inv_n;
  float var = ls2[0] * inv_n - mean * mean;
  float rstd = rsqrtf(var + 1e-6f);
  float a = alpha_ptr ? alpha_ptr[0] : alpha_const;
  for (int i = tid; i < elems; i += 256) {
    float v = x[base + i];
    int cc = g * chPerGroup + (i >> nshift);
    float gnv = (v - mean) * rstd * gamma[cc] + beta[cc];
    float r;
    if (ACT == 1)      r = gnv / (1.f + __expf(-gnv));
    else if (ACT == 2) r = 0.5f * gnv * (1.f + erff(gnv * 0.70710678118654752f));
    else               r = gnv;
    out[base + i] = HAS_RES ? (res[base + i] + a * r) : r;
  }
}

// ---------------- K6: IWT + residual: out = x + 0.1*iwt(s1, h_out) ----------------
__global__ __launch_bounds__(256) void k_iwt(const float* __restrict__ x,
                                             const float* __restrict__ s1,
                                             const float* __restrict__ hout,
                                             float* __restrict__ out) {
  int idx = blockIdx.x * 256 + threadIdx.x;  // B*C*32*32
  int w = idx & 31, h = (idx >> 5) & 31, c = (idx >> 10) & 127, b = idx >> 17;
  int n = h * 32 + w;
  float ll = s1[(size_t)(b * CC + c) * NPIX + n];
  float lh = hout[((size_t)b * C3 + c) * NPIX + n];
  float hl = hout[((size_t)b * C3 + CC + c) * NPIX + n];
  float hh = hout[((size_t)b * C3 + 2 * CC + c) * NPIX + n];
  float va = ll - lh - hl + hh;  // (2i, 2j)
  float vb = ll - lh + hl - hh;  // (2i+1, 2j)
  float vc = ll + lh - hl - hh;  // (2i, 2j+1)
  float vd = ll + lh + hl + hh;  // (2i+1, 2j+1)
  size_t xb = ((size_t)(b * CC + c) * HH + 2 * h) * HH + 2 * w;
  out[xb]          = x[xb]          + 0.1f * va;
  out[xb + 1]      = x[xb + 1]      + 0.1f * vc;
  out[xb + HH]     = x[xb + HH]     + 0.1f * vb;
  out[xb + HH + 1] = x[xb + HH + 1] + 0.1f * vd;
}

extern "C" void kernel_launch(void* const* d_in, const int* in_sizes, int n_in,
                              void* d_out, int out_size, void* d_ws, size_t ws_size,
                              hipStream_t stream) {
  const float* x         = (const float*)d_in[0];
  const float* qkv_w     = (const float*)d_in[1];
  const float* proj_w    = (const float*)d_in[2];
  const float* attn_gn_g = (const float*)d_in[3];
  const float* attn_gn_b = (const float*)d_in[4];
  const float* he_dw_w   = (const float*)d_in[5];
  const float* he_gn1_g  = (const float*)d_in[6];
  const float* he_gn1_b  = (const float*)d_in[7];
  const float* he_pw_w   = (const float*)d_in[8];
  const float* he_gn2_g  = (const float*)d_in[9];
  const float* he_gn2_b  = (const float*)d_in[10];
  const float* alpha     = (const float*)d_in[11];
  const float* ffn_w1    = (const float*)d_in[12];
  const float* ffn_gn1_g = (const float*)d_in[13];
  const float* ffn_gn1_b = (const float*)d_in[14];
  const float* ffn_w2    = (const float*)d_in[15];
  const float* ffn_gn2_g = (const float*)d_in[16];
  const float* ffn_gn2_b = (const float*)d_in[17];
  float* out = (float*)d_out;

  // Workspace layout (floats). Total 25,165,824 floats = 96 MB.
  float* ws = (float*)d_ws;
  float* ll   = ws;              // 1,048,576   (K1 -> K2a, K4b)
  float* high = ws + 1048576;    // 3,145,728   (K1 -> K5a, K5d)
  float* qkv  = ws + 4194304;    // 3,145,728   (K2a -> K2b); reused as y1 (K5a-K5c)
  float* qnkv = ws + 7340032;    // 3,145,728   qn|kn|v (K2b -> K3); reused as pw/h_out (K5c-K6)
  float* atto = ws + 10485760;   // 1,048,576   (K3 -> K4a)
  float* proj = ws + 11534336;   // 1,048,576   proj_raw -> s1 (K4a -> K6)
  float* f1   = ws + 12582912;   // 8,388,608   (K7a -> K7c, in-place gn)
  float* f3   = ws + 20971520;   // 4,194,304   (K7c -> K7d)
  float* qn = qnkv;
  float* kn = qnkv + 1048576;
  float* vv = qnkv + 2097152;
  float* y1 = qkv;
  float* pw = qnkv;

  // 1) DWT
  k_dwt<<<4096, 256, 0, stream>>>(x, ll, high);
  // 2) qkv = conv1x1(ll, qkv_w); split + l2norm
  k_conv1x1<128><<<dim3(4, 24, 8), 256, 0, stream>>>(ll, qkv_w, qkv, 384, 1024);
  k_qkvnorm<<<256, 256, 0, stream>>>(qkv, qn, kn, vv);
  // 3) sparse attention
  k_attn<<<16384, 256, 0, stream>>>(qn, kn, vv, atto);
  // 4) proj + groupnorm, s1 = ll + gn(proj)
  k_conv1x1<128><<<dim3(4, 8, 8), 256, 0, stream>>>(atto, proj_w, proj, 128, 1024);
  k_gn<0, true><<<256, 256, 0, stream>>>(proj, ll, proj, attn_gn_g, attn_gn_b,
                                         nullptr, 1.0f, 4, 1024, 10);
  // 5) high enhance
  k_dwconv<<<dim3(4, 384, 8), 256, 0, stream>>>(high, he_dw_w, y1);
  k_gn<1, false><<<256, 256, 0, stream>>>(y1, nullptr, y1, he_gn1_g, he_gn1_b,
                                          nullptr, 0.f, 12, 1024, 10);
  k_conv1x1<384><<<dim3(4, 24, 8), 256, 0, stream>>>(y1, he_pw_w, pw, 384, 1024);
  k_gn<0, true><<<256, 256, 0, stream>>>(pw, high, pw, he_gn2_g, he_gn2_b,
                                         alpha, 0.f, 12, 1024, 10);
  // 6) IWT + residual -> out (holds out1)
  k_iwt<<<4096, 256, 0, stream>>>(x, proj, pw, out);
  // 7) FFN: out += 0.1 * gn2(conv(gelu(gn1(conv(out)))))
  k_conv1x1<128><<<dim3(16, 16, 8), 256, 0, stream>>>(out, ffn_w1, f1, 256, 4096);
  k_gn<2, false><<<256, 256, 0, stream>>>(f1, nullptr, f1, ffn_gn1_g, ffn_gn1_b,
                                          nullptr, 0.f, 8, 4096, 12);
  k_conv1x1<256><<<dim3(16, 8, 8), 256, 0, stream>>>(f1, ffn_w2, f3, 128, 4096);
  k_gn<0, true><<<256, 256, 0, stream>>>(f3, out, out, ffn_gn2_g, ffn_gn2_b,
                                         nullptr, 0.1f, 4, 4096, 12);
  (void)in_sizes; (void)n_in; (void)out_size; (void)ws_size;
}

// Round 2
// 1135.816 us; speedup vs baseline: 1.1315x; 1.1315x over previous
//
#include <hip/hip_runtime.h>
#include <cstdint>
#include <cstddef>

// Dims (fixed by the problem)
#define BB 8
#define CC 128
#define C3 384
#define HH 64
#define H2 32
#define NPIX 1024   // 32*32
#define N4 4096     // 64*64
#define NHD 8
#define HD 16

// ---------------- K1: Haar DWT ----------------
__global__ __launch_bounds__(256) void k_dwt(const float* __restrict__ x,
                                             float* __restrict__ ll,
                                             float* __restrict__ high) {
  int idx = blockIdx.x * 256 + threadIdx.x;   // B*C*32*32 = 1,048,576
  int w = idx & 31, h = (idx >> 5) & 31, c = (idx >> 10) & 127, b = idx >> 17;
  const float* xp = x + ((size_t)(b * CC + c) * HH + 2 * h) * HH + 2 * w;
  float x1 = xp[0];
  float x2 = xp[HH];
  float x3 = xp[1];
  float x4 = xp[HH + 1];
  int n = h * H2 + w;
  ll[(size_t)(b * CC + c) * NPIX + n]              = 0.5f * ( x1 + x2 + x3 + x4);
  high[((size_t)b * C3 + c) * NPIX + n]            = 0.5f * (-x1 - x2 + x3 + x4);
  high[((size_t)b * C3 + CC + c) * NPIX + n]       = 0.5f * (-x1 + x2 - x3 + x4);
  high[((size_t)b * C3 + 2 * CC + c) * NPIX + n]   = 0.5f * ( x1 - x2 - x3 + x4);
}

// ---------------- Generic conv1x1 (GEMM) ----------------
template <int CIN>
__global__ __launch_bounds__(256) void k_conv1x1(const float* __restrict__ in,
                                                 const float* __restrict__ w,
                                                 float* __restrict__ out,
                                                 int Cout, int Npix) {
  __shared__ float lds[32 * 256];
  int tid = threadIdx.x;
  int n = blockIdx.x * 256 + tid;
  int o0 = blockIdx.y * 16;
  int b = blockIdx.z;
  const float* inb = in + (size_t)b * CIN * Npix + n;
  float acc[16];
#pragma unroll
  for (int o = 0; o < 16; ++o) acc[o] = 0.f;
  for (int c0 = 0; c0 < CIN; c0 += 32) {
    __syncthreads();
#pragma unroll
    for (int c = 0; c < 32; ++c) lds[c * 256 + tid] = inb[(size_t)(c0 + c) * Npix];
    __syncthreads();
#pragma unroll
    for (int c = 0; c < 32; ++c) {
      float vv = lds[c * 256 + tid];
#pragma unroll
      for (int o = 0; o < 16; ++o)
        acc[o] = fmaf(w[(size_t)(o0 + o) * CIN + c0 + c], vv, acc[o]);
    }
  }
  size_t ob = ((size_t)b * Cout + o0) * Npix + n;
#pragma unroll
  for (int o = 0; o < 16; ++o) out[ob + (size_t)o * Npix] = acc[o];
}

// ---------------- K2b: split qkv + l2norm q,k ----------------
__global__ __launch_bounds__(256) void k_qkvnorm(const float* __restrict__ qkv,
                                                 float* __restrict__ qn,
                                                 float* __restrict__ kn,
                                                 float* __restrict__ vout) {
  int idx = blockIdx.x * 256 + threadIdx.x;  // 65536 = B*NH*NPIX
  int n = idx & 1023, h = (idx >> 10) & 7, b = idx >> 13;
  const float* base = qkv + ((size_t)b * C3 + h * HD) * NPIX + n;
  float q[HD], k[HD], vv[HD];
  float sq = 0.f, sk = 0.f;
#pragma unroll
  for (int d = 0; d < HD; ++d) {
    q[d] = base[(size_t)d * NPIX];
    k[d] = base[(size_t)(CC + d) * NPIX];
    vv[d] = base[(size_t)(2 * CC + d) * NPIX];
    sq += q[d] * q[d];
    sk += k[d] * k[d];
  }
  float rq = 1.f / fmaxf(sqrtf(sq), 1e-12f);
  float rk = 1.f / fmaxf(sqrtf(sk), 1e-12f);
  float* qo = qn + (size_t)idx * HD;
  float* ko = kn + (size_t)idx * HD;
  float* vo = vout + (size_t)idx * HD;
#pragma unroll
  for (int d = 0; d < HD; ++d) { qo[d] = q[d] * rq; ko[d] = k[d] * rk; vo[d] = vv[d]; }
}

// ---------------- K3: sparse top-k attention ----------------
// Register-blocked: each wave handles 4 query rows; lane L covers keys
// {key_blk*64 + L}. K/V rows are loaded once per wave and reused for all
// 4 q-rows (4x less L2 traffic, 4x FMA per load vs 1-row-per-wave).
// Block = 4 waves = 16 q-rows of one (b,h); q vectors staged in LDS.
__global__ __launch_bounds__(256) void k_attn(const float* __restrict__ qn,
                                              const float* __restrict__ kn,
                                              const float* __restrict__ v,
                                              float* __restrict__ attn_out) {
  __shared__ float q_lds[16][16];
  int tid = threadIdx.x;
  int lane = tid & 63;
  int wave = tid >> 6;
  int blk = blockIdx.x;            // 4096 blocks; block rows = [blk*16, blk*16+16)
  int row0 = blk * 16;
  int bh = row0 >> 10;             // all 16 rows share bh (64 blocks per bh)
  // stage the block's 16 q-vectors (256 consecutive floats, coalesced)
  q_lds[tid >> 4][tid & 15] = qn[(size_t)row0 * HD + tid];
  __syncthreads();
  const float* kb = kn + (size_t)bh * NPIX * HD;
  const float* vb = v  + (size_t)bh * NPIX * HD;

  float s[4][16];   // scores: s[q][key_blk], key = key_blk*64 + lane
  // ---- phase 1: scores (K loaded once, used for 4 q-rows) ----
#pragma unroll
  for (int i = 0; i < 4; ++i) {          // 4 super-blocks of 256 keys
    float4 kr[4][4];
#pragma unroll
    for (int j = 0; j < 4; ++j) {
      const float* krow = kb + (size_t)(i * 256 + j * 64 + lane) * HD;
#pragma unroll
      for (int d4 = 0; d4 < 4; ++d4) kr[j][d4] = ((const float4*)krow)[d4];
    }
#pragma unroll
    for (int q = 0; q < 4; ++q) {
      const float4* qp = (const float4*)&q_lds[wave * 4 + q][0];
      float4 q0 = qp[0], q1 = qp[1], q2 = qp[2], q3 = qp[3];
#pragma unroll
      for (int j = 0; j < 4; ++j) {
        float acc = q0.x * kr[j][0].x + q0.y * kr[j][0].y + q0.z * kr[j][0].z + q0.w * kr[j][0].w
                  + q1.x * kr[j][1].x + q1.y * kr[j][1].y + q1.z * kr[j][1].z + q1.w * kr[j][1].w
                  + q2.x * kr[j][2].x + q2.y * kr[j][2].y + q2.z * kr[j][2].z + q2.w * kr[j][2].w
                  + q3.x * kr[j][3].x + q3.y * kr[j][3].y + q3.z * kr[j][3].z + q3.w * kr[j][3].w;
        acc *= 0.25f;                               // hd^-0.5
        s[q][i * 4 + j] = fminf(fmaxf(acc, -32.f), 32.f);
      }
    }
  }
  // ---- row max/min ----
  float mx[4], mn[4];
#pragma unroll
  for (int q = 0; q < 4; ++q) {
    float a = -1e30f, b2 = 1e30f;
#pragma unroll
    for (int k = 0; k < 16; ++k) { a = fmaxf(a, s[q][k]); b2 = fminf(b2, s[q][k]); }
#pragma unroll
    for (int off = 32; off > 0; off >>= 1) {
      a = fmaxf(a, __shfl_xor(a, off));
      b2 = fminf(b2, __shfl_xor(b2, off));
    }
    mx[q] = a; mn[q] = b2;
  }
  // ---- bisect per row for 512th-largest; counts packed 2-per-int ----
  float lo[4], hi[4];
#pragma unroll
  for (int q = 0; q < 4; ++q) { lo[q] = mn[q]; hi[q] = mx[q]; }
  for (int it = 0; it < 16; ++it) {
    float mid[4];
    int c01 = 0, c23 = 0;
#pragma unroll
    for (int q = 0; q < 4; ++q) {
      mid[q] = 0.5f * (lo[q] + hi[q]);
      int c = 0;
#pragma unroll
      for (int k = 0; k < 16; ++k) c += (s[q][k] >= mid[q]) ? 1 : 0;
      if (q == 0) c01 = c;
      else if (q == 1) c01 |= c << 16;
      else if (q == 2) c23 = c;
      else c23 |= c << 16;
    }
#pragma unroll
    for (int off = 32; off > 0; off >>= 1) {
      c01 += __shfl_xor(c01, off);
      c23 += __shfl_xor(c23, off);
    }
    int cnt[4] = { c01 & 0xFFFF, c01 >> 16, c23 & 0xFFFF, c23 >> 16 };
#pragma unroll
    for (int q = 0; q < 4; ++q) {
      if (cnt[q] >= 512) lo[q] = mid[q]; else hi[q] = mid[q];
    }
  }
  // ---- masked softmax (p kept unnormalized; normalize at the end) ----
  float inv[4];
#pragma unroll
  for (int q = 0; q < 4; ++q) {
    float sum = 0.f;
#pragma unroll
    for (int k = 0; k < 16; ++k) {
      float p = (s[q][k] >= lo[q]) ? __expf(s[q][k] - mx[q]) : 0.f;
      s[q][k] = p;
      sum += p;
    }
#pragma unroll
    for (int off = 32; off > 0; off >>= 1) sum += __shfl_xor(sum, off);
    inv[q] = 1.f / sum;
  }
  // ---- phase 2: AV (V loaded once, used for 4 q-rows) ----
  float o[4][16];
#pragma unroll
  for (int q = 0; q < 4; ++q)
#pragma unroll
    for (int d = 0; d < 16; ++d) o[q][d] = 0.f;
#pragma unroll
  for (int i = 0; i < 4; ++i) {
    float4 vr[4][4];
#pragma unroll
    for (int j = 0; j < 4; ++j) {
      const float* vrow = vb + (size_t)(i * 256 + j * 64 + lane) * HD;
#pragma unroll
      for (int d4 = 0; d4 < 4; ++d4) vr[j][d4] = ((const float4*)vrow)[d4];
    }
#pragma unroll
    for (int q = 0; q < 4; ++q) {
#pragma unroll
      for (int j = 0; j < 4; ++j) {
        float pj = s[q][i * 4 + j];
        o[q][0]  = fmaf(pj, vr[j][0].x, o[q][0]);
        o[q][1]  = fmaf(pj, vr[j][0].y, o[q][1]);
        o[q][2]  = fmaf(pj, vr[j][0].z, o[q][2]);
        o[q][3]  = fmaf(pj, vr[j][0].w, o[q][3]);
        o[q][4]  = fmaf(pj, vr[j][1].x, o[q][4]);
        o[q][5]  = fmaf(pj, vr[j][1].y, o[q][5]);
        o[q][6]  = fmaf(pj, vr[j][1].z, o[q][6]);
        o[q][7]  = fmaf(pj, vr[j][1].w, o[q][7]);
        o[q][8]  = fmaf(pj, vr[j][2].x, o[q][8]);
        o[q][9]  = fmaf(pj, vr[j][2].y, o[q][9]);
        o[q][10] = fmaf(pj, vr[j][2].z, o[q][10]);
        o[q][11] = fmaf(pj, vr[j][2].w, o[q][11]);
        o[q][12] = fmaf(pj, vr[j][3].x, o[q][12]);
        o[q][13] = fmaf(pj, vr[j][3].y, o[q][13]);
        o[q][14] = fmaf(pj, vr[j][3].z, o[q][14]);
        o[q][15] = fmaf(pj, vr[j][3].w, o[q][15]);
      }
    }
  }
  // ---- fold-transpose reduce: lane (L&15) ends with total for dim L&15 ----
  int b = bh >> 3, h = bh & 7;
#pragma unroll
  for (int q = 0; q < 4; ++q) {
    float A[16], R[16];
#pragma unroll
    for (int i = 0; i < 16; ++i) A[i] = o[q][i];
    // step 0 (mask 1): 16 -> 8
#pragma unroll
    for (int i = 0; i < 16; ++i) R[i] = __shfl_xor(A[i], 1);
    bool m0 = (lane & 1) != 0;
    float B8[8];
#pragma unroll
    for (int p = 0; p < 8; ++p)
      B8[p] = m0 ? (A[2 * p + 1] + R[2 * p + 1]) : (A[2 * p] + R[2 * p]);
    // step 1 (mask 2): 8 -> 4
    float R8[8];
#pragma unroll
    for (int p = 0; p < 8; ++p) R8[p] = __shfl_xor(B8[p], 2);
    bool m1 = (lane & 2) != 0;
    float B4[4];
#pragma unroll
    for (int p = 0; p < 4; ++p)
      B4[p] = m1 ? (B8[2 * p + 1] + R8[2 * p + 1]) : (B8[2 * p] + R8[2 * p]);
    // step 2 (mask 4): 4 -> 2
    float R4[4];
#pragma unroll
    for (int p = 0; p < 4; ++p) R4[p] = __shfl_xor(B4[p], 4);
    bool m2 = (lane & 4) != 0;
    float B2[2];
#pragma unroll
    for (int p = 0; p < 2; ++p)
      B2[p] = m2 ? (B4[2 * p + 1] + R4[2 * p + 1]) : (B4[2 * p] + R4[2 * p]);
    // step 3 (mask 8): 2 -> 1
    float R2[2];
    R2[0] = __shfl_xor(B2[0], 8);
    R2[1] = __shfl_xor(B2[1], 8);
    bool m3 = (lane & 8) != 0;
    float w1 = m3 ? (B2[1] + R2[1]) : (B2[0] + R2[0]);
    // scalar steps (mask 16, 32): reduce across the 4 lane-groups
    w1 += __shfl_xor(w1, 16);
    w1 += __shfl_xor(w1, 32);
    // lane L (<16) now holds total for dim d = L; scale and store
    if (lane < 16) {
      int r = row0 + wave * 4 + q;
      int n = r & 1023;
      attn_out[((size_t)(b * CC + h * HD + lane) * NPIX) + n] = w1 * inv[q];
    }
  }
}

// ---------------- K5a: depthwise 3x3 SAME conv ----------------
__global__ __launch_bounds__(256) void k_dwconv(const float* __restrict__ in,
                                                const float* __restrict__ w,
                                                float* __restrict__ out) {
  int n = blockIdx.x * 256 + threadIdx.x;
  int c = blockIdx.y, b = blockIdx.z;
  int i = n >> 5, j = n & 31;
  const float* inb = in + ((size_t)b * C3 + c) * NPIX;
  const float* wc = w + c * 9;
  float acc = 0.f;
#pragma unroll
  for (int di = -1; di <= 1; ++di) {
    int ii = i + di;
    if (ii < 0 || ii > 31) continue;
#pragma unroll
    for (int dj = -1; dj <= 1; ++dj) {
      int jj = j + dj;
      if (jj < 0 || jj > 31) continue;
      acc += inb[ii * 32 + jj] * wc[(di + 1) * 3 + (dj + 1)];
    }
  }
  out[((size_t)b * C3 + c) * NPIX + n] = acc;
}

// ---------------- GroupNorm (32 groups) + fused epilogue ----------------
template <int ACT, bool HAS_RES>
__global__ __launch_bounds__(256) void k_gn(const float* __restrict__ x,
                                            const float* __restrict__ res,
                                            float* __restrict__ out,
                                            const float* __restrict__ gamma,
                                            const float* __restrict__ beta,
                                            const float* __restrict__ alpha_ptr,
                                            float alpha_const,
                                            int chPerGroup, int Npix, int nshift) {
  int g = blockIdx.x & 31, b = blockIdx.x >> 5;
  int Cout = 32 * chPerGroup;
  int elems = chPerGroup * Npix;
  size_t base = ((size_t)b * Cout + g * chPerGroup) * Npix;
  int tid = threadIdx.x;
  float s = 0.f, s2 = 0.f;
  for (int i = tid; i < elems; i += 256) {
    float v = x[base + i];
    s += v; s2 += v * v;
  }
  __shared__ float ls[256], ls2[256];
  ls[tid] = s; ls2[tid] = s2;
  __syncthreads();
  for (int st = 128; st > 0; st >>= 1) {
    if (tid < st) { ls[tid] += ls[tid + st]; ls2[tid] += ls2[tid + st]; }
    __syncthreads();
  }
  float inv_n = 1.f / (float)elems;
  float mean = ls[0] * inv_n;
  float var = ls2[0] * inv_n - mean * mean;
  float rstd = rsqrtf(var + 1e-6f);
  float a = alpha_ptr ? alpha_ptr[0] : alpha_const;
  for (int i = tid; i < elems; i += 256) {
    float v = x[base + i];
    int cc = g * chPerGroup + (i >> nshift);
    float gnv = (v - mean) * rstd * gamma[cc] + beta[cc];
    float r;
    if (ACT == 1)      r = gnv / (1.f + __expf(-gnv));
    else if (ACT == 2) r = 0.5f * gnv * (1.f + erff(gnv * 0.70710678118654752f));
    else               r = gnv;
    out[base + i] = HAS_RES ? (res[base + i] + a * r) : r;
  }
}

// ---------------- K6: IWT + residual ----------------
__global__ __launch_bounds__(256) void k_iwt(const float* __restrict__ x,
                                             const float* __restrict__ s1,
                                             const float* __restrict__ hout,
                                             float* __restrict__ out) {
  int idx = blockIdx.x * 256 + threadIdx.x;  // B*C*32*32
  int w = idx & 31, h = (idx >> 5) & 31, c = (idx >> 10) & 127, b = idx >> 17;
  int n = h * 32 + w;
  float ll = s1[(size_t)(b * CC + c) * NPIX + n];
  float lh = hout[((size_t)b * C3 + c) * NPIX + n];
  float hl = hout[((size_t)b * C3 + CC + c) * NPIX + n];
  float hh = hout[((size_t)b * C3 + 2 * CC + c) * NPIX + n];
  float va = ll - lh - hl + hh;
  float vb = ll - lh + hl - hh;
  float vc = ll + lh - hl - hh;
  float vd = ll + lh + hl + hh;
  size_t xb = ((size_t)(b * CC + c) * HH + 2 * h) * HH + 2 * w;
  out[xb]          = x[xb]          + 0.1f * va;
  out[xb + 1]      = x[xb + 1]      + 0.1f * vc;
  out[xb + HH]     = x[xb + HH]     + 0.1f * vb;
  out[xb + HH + 1] = x[xb + HH + 1] + 0.1f * vd;
}

extern "C" void kernel_launch(void* const* d_in, const int* in_sizes, int n_in,
                              void* d_out, int out_size, void* d_ws, size_t ws_size,
                              hipStream_t stream) {
  const float* x         = (const float*)d_in[0];
  const float* qkv_w     = (const float*)d_in[1];
  const float* proj_w    = (const float*)d_in[2];
  const float* attn_gn_g = (const float*)d_in[3];
  const float* attn_gn_b = (const float*)d_in[4];
  const float* he_dw_w   = (const float*)d_in[5];
  const float* he_gn1_g  = (const float*)d_in[6];
  const float* he_gn1_b  = (const float*)d_in[7];
  const float* he_pw_w   = (const float*)d_in[8];
  const float* he_gn2_g  = (const float*)d_in[9];
  const float* he_gn2_b  = (const float*)d_in[10];
  const float* alpha     = (const float*)d_in[11];
  const float* ffn_w1    = (const float*)d_in[12];
  const float* ffn_gn1_g = (const float*)d_in[13];
  const float* ffn_gn1_b = (const float*)d_in[14];
  const float* ffn_w2    = (const float*)d_in[15];
  const float* ffn_gn2_g = (const float*)d_in[16];
  const float* ffn_gn2_b = (const float*)d_in[17];
  float* out = (float*)d_out;

  float* ws = (float*)d_ws;
  float* ll   = ws;              // 1,048,576
  float* high = ws + 1048576;    // 3,145,728
  float* qkv  = ws + 4194304;    // 3,145,728 ; reused as y1
  float* qnkv = ws + 7340032;    // 3,145,728 ; qn|kn|v ; reused as pw/h_out
  float* atto = ws + 10485760;   // 1,048,576
  float* proj = ws + 11534336;   // 1,048,576
  float* f1   = ws + 12582912;   // 8,388,608
  float* f3   = ws + 20971520;   // 4,194,304
  float* qn = qnkv;
  float* kn = qnkv + 1048576;
  float* vv = qnkv + 2097152;
  float* y1 = qkv;
  float* pw = qnkv;

  // 1) DWT
  k_dwt<<<4096, 256, 0, stream>>>(x, ll, high);
  // 2) qkv = conv1x1(ll, qkv_w); split + l2norm
  k_conv1x1<128><<<dim3(4, 24, 8), 256, 0, stream>>>(ll, qkv_w, qkv, 384, 1024);
  k_qkvnorm<<<256, 256, 0, stream>>>(qkv, qn, kn, vv);
  // 3) sparse attention (4 q-rows per wave)
  k_attn<<<4096, 256, 0, stream>>>(qn, kn, vv, atto);
  // 4) proj + groupnorm, s1 = ll + gn(proj)
  k_conv1x1<128><<<dim3(4, 8, 8), 256, 0, stream>>>(atto, proj_w, proj, 128, 1024);
  k_gn<0, true><<<256, 256, 0, stream>>>(proj, ll, proj, attn_gn_g, attn_gn_b,
                                         nullptr, 1.0f, 4, 1024, 10);
  // 5) high enhance
  k_dwconv<<<dim3(4, 384, 8), 256, 0, stream>>>(high, he_dw_w, y1);
  k_gn<1, false><<<256, 256, 0, stream>>>(y1, nullptr, y1, he_gn1_g, he_gn1_b,
                                          nullptr, 0.f, 12, 1024, 10);
  k_conv1x1<384><<<dim3(4, 24, 8), 256, 0, stream>>>(y1, he_pw_w, pw, 384, 1024);
  k_gn<0, true><<<256, 256, 0, stream>>>(pw, high, pw, he_gn2_g, he_gn2_b,
                                         alpha, 0.f, 12, 1024, 10);
  // 6) IWT + residual -> out
  k_iwt<<<4096, 256, 0, stream>>>(x, proj, pw, out);
  // 7) FFN
  k_conv1x1<128><<<dim3(16, 16, 8), 256, 0, stream>>>(out, ffn_w1, f1, 256, 4096);
  k_gn<2, false><<<256, 256, 0, stream>>>(f1, nullptr, f1, ffn_gn1_g, ffn_gn1_b,
                                          nullptr, 0.f, 8, 4096, 12);
  k_conv1x1<256><<<dim3(16, 8, 8), 256, 0, stream>>>(f1, ffn_w2, f3, 128, 4096);
  k_gn<0, true><<<256, 256, 0, stream>>>(f3, out, out, ffn_gn2_g, ffn_gn2_b,
                                         nullptr, 0.1f, 4, 4096, 12);
  (void)in_sizes; (void)n_in; (void)out_size; (void)ws_size;
}

// Round 3
// 641.943 us; speedup vs baseline: 2.0020x; 1.7693x over previous
//
#include <hip/hip_runtime.h>
#include <hip/hip_fp16.h>
#include <cstdint>
#include <cstddef>

// Dims (fixed by the problem)
#define BB 8
#define CC 128
#define C3 384
#define HH 64
#define H2 32
#define NPIX 1024   // 32*32
#define N4 4096     // 64*64
#define NHD 8
#define HD 16

// ---------------- K1: Haar DWT ----------------
__global__ __launch_bounds__(256) void k_dwt(const float* __restrict__ x,
                                             float* __restrict__ ll,
                                             float* __restrict__ high) {
  int idx = blockIdx.x * 256 + threadIdx.x;   // B*C*32*32 = 1,048,576
  int w = idx & 31, h = (idx >> 5) & 31, c = (idx >> 10) & 127, b = idx >> 17;
  const float* xp = x + ((size_t)(b * CC + c) * HH + 2 * h) * HH + 2 * w;
  float x1 = xp[0];
  float x2 = xp[HH];
  float x3 = xp[1];
  float x4 = xp[HH + 1];
  int n = h * H2 + w;
  ll[(size_t)(b * CC + c) * NPIX + n]              = 0.5f * ( x1 + x2 + x3 + x4);
  high[((size_t)b * C3 + c) * NPIX + n]            = 0.5f * (-x1 - x2 + x3 + x4);
  high[((size_t)b * C3 + CC + c) * NPIX + n]       = 0.5f * (-x1 + x2 - x3 + x4);
  high[((size_t)b * C3 + 2 * CC + c) * NPIX + n]   = 0.5f * ( x1 - x2 - x3 + x4);
}

// ---------------- conv1x1: pure-register GEMV per pixel ----------------
// out[b,o,n] = sum_c w[o,c]*in[b,c,n]. Thread owns P consecutive pixels and
// 16 output channels. No LDS: each thread only ever needs its own pixels'
// inputs; weights are wave-uniform -> scalar loads + s-operand v_fmac.
template <int CIN, int P>
__global__ __launch_bounds__(256) void k_conv1x1(const float* __restrict__ in,
                                                 const float* __restrict__ w,
                                                 float* __restrict__ out,
                                                 int Cout, int Npix) {
  int tid = threadIdx.x;
  int n0 = (blockIdx.x * 256 + tid) * P;
  int o0 = blockIdx.y * 16;
  int b = blockIdx.z;
  const float* inb = in + (size_t)b * CIN * Npix + n0;
  const float* wb = w + (size_t)o0 * CIN;
  float acc[16][P];
#pragma unroll
  for (int o = 0; o < 16; ++o)
#pragma unroll
    for (int p = 0; p < P; ++p) acc[o][p] = 0.f;

  for (int c0 = 0; c0 < CIN; c0 += 8) {
#pragma unroll
    for (int c = 0; c < 8; ++c) {
      float vv[P];
      const float* ip = inb + (size_t)(c0 + c) * Npix;
      if constexpr (P == 4) {
        float4 t = *(const float4*)ip;
        vv[0] = t.x; vv[1] = t.y; vv[2] = t.z; vv[3] = t.w;
      } else if constexpr (P == 2) {
        float2 t = *(const float2*)ip;
        vv[0] = t.x; vv[1] = t.y;
      } else {
        vv[0] = ip[0];
      }
#pragma unroll
      for (int o = 0; o < 16; ++o) {
        float wc = wb[(size_t)o * CIN + c0 + c];   // uniform -> s_load
#pragma unroll
        for (int p = 0; p < P; ++p) acc[o][p] = fmaf(wc, vv[p], acc[o][p]);
      }
    }
  }
  size_t ob = ((size_t)b * Cout + o0) * Npix + n0;
#pragma unroll
  for (int o = 0; o < 16; ++o) {
    float* op = out + ob + (size_t)o * Npix;
    if constexpr (P == 4) {
      *(float4*)op = make_float4(acc[o][0], acc[o][1], acc[o][2], acc[o][3]);
    } else if constexpr (P == 2) {
      *(float2*)op = make_float2(acc[o][0], acc[o][1]);
    } else {
      op[0] = acc[o][0];
    }
  }
}

// ---------------- K2b: split qkv + l2norm q,k ----------------
__global__ __launch_bounds__(256) void k_qkvnorm(const float* __restrict__ qkv,
                                                 float* __restrict__ qn,
                                                 float* __restrict__ kn,
                                                 float* __restrict__ vout) {
  int idx = blockIdx.x * 256 + threadIdx.x;  // 65536 = B*NH*NPIX
  int n = idx & 1023, h = (idx >> 10) & 7, b = idx >> 13;
  const float* base = qkv + ((size_t)b * C3 + h * HD) * NPIX + n;
  float q[HD], k[HD], vv[HD];
  float sq = 0.f, sk = 0.f;
#pragma unroll
  for (int d = 0; d < HD; ++d) {
    q[d] = base[(size_t)d * NPIX];
    k[d] = base[(size_t)(CC + d) * NPIX];
    vv[d] = base[(size_t)(2 * CC + d) * NPIX];
    sq += q[d] * q[d];
    sk += k[d] * k[d];
  }
  float rq = 1.f / fmaxf(sqrtf(sq), 1e-12f);
  float rk = 1.f / fmaxf(sqrtf(sk), 1e-12f);
  float4* qo = (float4*)(qn + (size_t)idx * HD);
  float4* ko = (float4*)(kn + (size_t)idx * HD);
  float4* vo = (float4*)(vout + (size_t)idx * HD);
#pragma unroll
  for (int d4 = 0; d4 < 4; ++d4) {
    qo[d4] = make_float4(q[4*d4]*rq, q[4*d4+1]*rq, q[4*d4+2]*rq, q[4*d4+3]*rq);
    ko[d4] = make_float4(k[4*d4]*rk, k[4*d4+1]*rk, k[4*d4+2]*rk, k[4*d4+3]*rk);
    vo[d4] = make_float4(vv[4*d4], vv[4*d4+1], vv[4*d4+2], vv[4*d4+3]);
  }
}

// ---------------- K3: sparse top-k attention ----------------
// 4 q-rows per wave, lane L covers keys {16 blocks of 64}+L. Scores bounded:
// |s| = |q_hat . k_hat| * 0.25 <= 0.25 -> no clip, no max-subtract, fixed
// bisection bounds. Bisection counts via ballot+popcll (SALU accumulate).
// p packed as half2 for the AV phase.
__global__ __launch_bounds__(256) void k_attn(const float* __restrict__ qn,
                                              const float* __restrict__ kn,
                                              const float* __restrict__ v,
                                              float* __restrict__ attn_out) {
  int tid = threadIdx.x;
  int lane = tid & 63;
  int wave = __builtin_amdgcn_readfirstlane(tid >> 6);
  int blk = blockIdx.x;            // 4096 blocks; 64 blocks per (b,h)
  int bh = blk >> 6;
  int row0w = blk * 16 + wave * 4; // this wave's 4 query rows
  // q loads: address uniform per wave -> scalar loads (SGPR q)
  const float* qb = qn + (size_t)row0w * HD;
  float qs[4][16];
#pragma unroll
  for (int q = 0; q < 4; ++q)
#pragma unroll
    for (int d = 0; d < 16; ++d) qs[q][d] = qb[q * 16 + d];

  const float* kb = kn + (size_t)bh * NPIX * HD;
  const float* vb = v  + (size_t)bh * NPIX * HD;

  // ---- phase 1: scores ----
  float s[4][16];
#pragma unroll 4
  for (int i = 0; i < 16; ++i) {
    const float* krow = kb + (size_t)(i * 64 + lane) * HD;
    float kr[16];
#pragma unroll
    for (int d4 = 0; d4 < 4; ++d4) {
      float4 t = ((const float4*)krow)[d4];
      kr[4*d4] = t.x; kr[4*d4+1] = t.y; kr[4*d4+2] = t.z; kr[4*d4+3] = t.w;
    }
#pragma unroll
    for (int q = 0; q < 4; ++q) {
      float acc = 0.f;
#pragma unroll
      for (int d = 0; d < 16; ++d) acc = fmaf(qs[q][d], kr[d], acc);
      s[q][i] = acc * 0.25f;
    }
  }

  // ---- bisect for 512th-largest: ballot + popc, scalar lo/hi ----
  float lo[4], hi[4];
#pragma unroll
  for (int q = 0; q < 4; ++q) { lo[q] = -0.26f; hi[q] = 0.26f; }
  for (int it = 0; it < 14; ++it) {
#pragma unroll
    for (int q = 0; q < 4; ++q) {
      float mid = 0.5f * (lo[q] + hi[q]);
      int c = 0;
#pragma unroll
      for (int k = 0; k < 16; ++k)
        c += __popcll(__ballot(s[q][k] >= mid));
      if (c >= 512) lo[q] = mid; else hi[q] = mid;
    }
  }

  // ---- masked softmax; pack p to half2 ----
  float inv[4];
  __half2 p2[4][8];
#pragma unroll
  for (int q = 0; q < 4; ++q) {
    float pv[16];
    float sum = 0.f;
#pragma unroll
    for (int k = 0; k < 16; ++k) {
      float e = __expf(s[q][k]);        // s in [-0.25,0.25], no max-sub needed
      pv[k] = (s[q][k] >= lo[q]) ? e : 0.f;
      sum += pv[k];
    }
#pragma unroll
    for (int off = 32; off > 0; off >>= 1) sum += __shfl_xor(sum, off);
    inv[q] = 1.f / sum;
#pragma unroll
    for (int k = 0; k < 16; k += 2)
      p2[q][k >> 1] = __floats2half2_rn(pv[k], pv[k + 1]);
  }

  // ---- phase 2: AV ----
  float ov[4][16];
#pragma unroll
  for (int q = 0; q < 4; ++q)
#pragma unroll
    for (int d = 0; d < 16; ++d) ov[q][d] = 0.f;
#pragma unroll 4
  for (int i = 0; i < 16; ++i) {
    const float* vrow = vb + (size_t)(i * 64 + lane) * HD;
    float vr[16];
#pragma unroll
    for (int d4 = 0; d4 < 4; ++d4) {
      float4 t = ((const float4*)vrow)[d4];
      vr[4*d4] = t.x; vr[4*d4+1] = t.y; vr[4*d4+2] = t.z; vr[4*d4+3] = t.w;
    }
#pragma unroll
    for (int q = 0; q < 4; ++q) {
      __half2 h2 = p2[q][i >> 1];
      float pj = (i & 1) ? __high2float(h2) : __low2float(h2);
#pragma unroll
      for (int d = 0; d < 16; ++d) ov[q][d] = fmaf(pj, vr[d], ov[q][d]);
    }
  }

  // ---- fold-transpose reduce: lane (L&15) ends with total for dim L&15 ----
  int b = bh >> 3, h = bh & 7;
#pragma unroll
  for (int q = 0; q < 4; ++q) {
    float A[16], R[16];
#pragma unroll
    for (int i = 0; i < 16; ++i) A[i] = ov[q][i];
#pragma unroll
    for (int i = 0; i < 16; ++i) R[i] = __shfl_xor(A[i], 1);
    bool m0 = (lane & 1) != 0;
    float B8[8];
#pragma unroll
    for (int p = 0; p < 8; ++p)
      B8[p] = m0 ? (A[2 * p + 1] + R[2 * p + 1]) : (A[2 * p] + R[2 * p]);
    float R8[8];
#pragma unroll
    for (int p = 0; p < 8; ++p) R8[p] = __shfl_xor(B8[p], 2);
    bool m1 = (lane & 2) != 0;
    float B4[4];
#pragma unroll
    for (int p = 0; p < 4; ++p)
      B4[p] = m1 ? (B8[2 * p + 1] + R8[2 * p + 1]) : (B8[2 * p] + R8[2 * p]);
    float R4[4];
#pragma unroll
    for (int p = 0; p < 4; ++p) R4[p] = __shfl_xor(B4[p], 4);
    bool m2 = (lane & 4) != 0;
    float B2[2];
#pragma unroll
    for (int p = 0; p < 2; ++p)
      B2[p] = m2 ? (B4[2 * p + 1] + R4[2 * p + 1]) : (B4[2 * p] + R4[2 * p]);
    float R2[2];
    R2[0] = __shfl_xor(B2[0], 8);
    R2[1] = __shfl_xor(B2[1], 8);
    bool m3 = (lane & 8) != 0;
    float w1 = m3 ? (B2[1] + R2[1]) : (B2[0] + R2[0]);
    w1 += __shfl_xor(w1, 16);
    w1 += __shfl_xor(w1, 32);
    if (lane < 16) {
      int r = row0w + q;
      int n = r & 1023;
      attn_out[((size_t)(b * CC + h * HD + lane) * NPIX) + n] = w1 * inv[q];
    }
  }
}

// ---------------- K5a: depthwise 3x3 SAME conv ----------------
__global__ __launch_bounds__(256) void k_dwconv(const float* __restrict__ in,
                                                const float* __restrict__ w,
                                                float* __restrict__ out) {
  int n = blockIdx.x * 256 + threadIdx.x;
  int c = blockIdx.y, b = blockIdx.z;
  int i = n >> 5, j = n & 31;
  const float* inb = in + ((size_t)b * C3 + c) * NPIX;
  const float* wc = w + c * 9;
  float acc = 0.f;
#pragma unroll
  for (int di = -1; di <= 1; ++di) {
    int ii = i + di;
    if (ii < 0 || ii > 31) continue;
#pragma unroll
    for (int dj = -1; dj <= 1; ++dj) {
      int jj = j + dj;
      if (jj < 0 || jj > 31) continue;
      acc += inb[ii * 32 + jj] * wc[(di + 1) * 3 + (dj + 1)];
    }
  }
  out[((size_t)b * C3 + c) * NPIX + n] = acc;
}

// ---------------- GroupNorm (32 groups) + fused epilogue, float4, 512 thr ----
// ACT: 0 none, 1 silu, 2 exact gelu.  HAS_RES: out = res + a*gn.
template <int ACT, bool HAS_RES>
__global__ __launch_bounds__(512) void k_gn(const float* __restrict__ x,
                                            const float* __restrict__ res,
                                            float* __restrict__ out,
                                            const float* __restrict__ gamma,
                                            const float* __restrict__ beta,
                                            const float* __restrict__ alpha_ptr,
                                            float alpha_const,
                                            int chPerGroup, int Npix, int nshift) {
  int g = blockIdx.x & 31, b = blockIdx.x >> 5;
  int Cout = 32 * chPerGroup;
  int elems = chPerGroup * Npix;
  int nv = elems >> 2;
  size_t base = ((size_t)b * Cout + g * chPerGroup) * Npix;
  const float4* xv = (const float4*)(x + base);
  int tid = threadIdx.x;
  float s = 0.f, s2 = 0.f;
  for (int i = tid; i < nv; i += 512) {
    float4 v = xv[i];
    s += v.x + v.y + v.z + v.w;
    s2 += v.x * v.x + v.y * v.y + v.z * v.z + v.w * v.w;
  }
  __shared__ float ls[512], ls2[512];
  ls[tid] = s; ls2[tid] = s2;
  __syncthreads();
  for (int st = 256; st > 0; st >>= 1) {
    if (tid < st) { ls[tid] += ls[tid + st]; ls2[tid] += ls2[tid + st]; }
    __syncthreads();
  }
  float inv_n = 1.f / (float)elems;
  float mean = ls[0] * inv_n;
  float var = ls2[0] * inv_n - mean * mean;
  float rstd = rsqrtf(var + 1e-6f);
  float a = alpha_ptr ? alpha_ptr[0] : alpha_const;
  const float4* rv = (const float4*)(res + base);
  float4* ov = (float4*)(out + base);
  int cshift = nshift - 2;
  for (int i = tid; i < nv; i += 512) {
    float4 v = xv[i];
    int cc = g * chPerGroup + (i >> cshift);
    float gm = gamma[cc], bt = beta[cc];
    float r[4] = {v.x, v.y, v.z, v.w};
#pragma unroll
    for (int p = 0; p < 4; ++p) {
      float gnv = (r[p] - mean) * rstd * gm + bt;
      if (ACT == 1)      r[p] = gnv / (1.f + __expf(-gnv));
      else if (ACT == 2) r[p] = 0.5f * gnv * (1.f + erff(gnv * 0.70710678118654752f));
      else               r[p] = gnv;
    }
    float4 o;
    if (HAS_RES) {
      float4 rr = rv[i];
      o = make_float4(rr.x + a * r[0], rr.y + a * r[1], rr.z + a * r[2], rr.w + a * r[3]);
    } else {
      o = make_float4(r[0], r[1], r[2], r[3]);
    }
    ov[i] = o;
  }
}

// ---------------- K6: IWT + residual ----------------
__global__ __launch_bounds__(256) void k_iwt(const float* __restrict__ x,
                                             const float* __restrict__ s1,
                                             const float* __restrict__ hout,
                                             float* __restrict__ out) {
  int idx = blockIdx.x * 256 + threadIdx.x;  // B*C*32*32
  int w = idx & 31, h = (idx >> 5) & 31, c = (idx >> 10) & 127, b = idx >> 17;
  int n = h * 32 + w;
  float ll = s1[(size_t)(b * CC + c) * NPIX + n];
  float lh = hout[((size_t)b * C3 + c) * NPIX + n];
  float hl = hout[((size_t)b * C3 + CC + c) * NPIX + n];
  float hh = hout[((size_t)b * C3 + 2 * CC + c) * NPIX + n];
  float va = ll - lh - hl + hh;
  float vb = ll - lh + hl - hh;
  float vc = ll + lh - hl - hh;
  float vd = ll + lh + hl + hh;
  size_t xb = ((size_t)(b * CC + c) * HH + 2 * h) * HH + 2 * w;
  out[xb]          = x[xb]          + 0.1f * va;
  out[xb + 1]      = x[xb + 1]      + 0.1f * vc;
  out[xb + HH]     = x[xb + HH]     + 0.1f * vb;
  out[xb + HH + 1] = x[xb + HH + 1] + 0.1f * vd;
}

extern "C" void kernel_launch(void* const* d_in, const int* in_sizes, int n_in,
                              void* d_out, int out_size, void* d_ws, size_t ws_size,
                              hipStream_t stream) {
  const float* x         = (const float*)d_in[0];
  const float* qkv_w     = (const float*)d_in[1];
  const float* proj_w    = (const float*)d_in[2];
  const float* attn_gn_g = (const float*)d_in[3];
  const float* attn_gn_b = (const float*)d_in[4];
  const float* he_dw_w   = (const float*)d_in[5];
  const float* he_gn1_g  = (const float*)d_in[6];
  const float* he_gn1_b  = (const float*)d_in[7];
  const float* he_pw_w   = (const float*)d_in[8];
  const float* he_gn2_g  = (const float*)d_in[9];
  const float* he_gn2_b  = (const float*)d_in[10];
  const float* alpha     = (const float*)d_in[11];
  const float* ffn_w1    = (const float*)d_in[12];
  const float* ffn_gn1_g = (const float*)d_in[13];
  const float* ffn_gn1_b = (const float*)d_in[14];
  const float* ffn_w2    = (const float*)d_in[15];
  const float* ffn_gn2_g = (const float*)d_in[16];
  const float* ffn_gn2_b = (const float*)d_in[17];
  float* out = (float*)d_out;

  float* ws = (float*)d_ws;
  float* ll   = ws;              // 1,048,576
  float* high = ws + 1048576;    // 3,145,728
  float* qkv  = ws + 4194304;    // 3,145,728 ; reused as y1
  float* qnkv = ws + 7340032;    // 3,145,728 ; qn|kn|v ; reused as pw/h_out
  float* atto = ws + 10485760;   // 1,048,576
  float* proj = ws + 11534336;   // 1,048,576
  float* f1   = ws + 12582912;   // 8,388,608
  float* f3   = ws + 20971520;   // 4,194,304
  float* qn = qnkv;
  float* kn = qnkv + 1048576;
  float* vv = qnkv + 2097152;
  float* y1 = qkv;
  float* pw = qnkv;

  // 1) DWT
  k_dwt<<<4096, 256, 0, stream>>>(x, ll, high);
  // 2) qkv = conv1x1(ll, qkv_w); split + l2norm
  k_conv1x1<128, 2><<<dim3(2, 24, 8), 256, 0, stream>>>(ll, qkv_w, qkv, 384, 1024);
  k_qkvnorm<<<256, 256, 0, stream>>>(qkv, qn, kn, vv);
  // 3) sparse attention (4 q-rows per wave)
  k_attn<<<4096, 256, 0, stream>>>(qn, kn, vv, atto);
  // 4) proj + groupnorm, s1 = ll + gn(proj)
  k_conv1x1<128, 1><<<dim3(4, 8, 8), 256, 0, stream>>>(atto, proj_w, proj, 128, 1024);
  k_gn<0, true><<<256, 512, 0, stream>>>(proj, ll, proj, attn_gn_g, attn_gn_b,
                                         nullptr, 1.0f, 4, 1024, 10);
  // 5) high enhance
  k_dwconv<<<dim3(4, 384, 8), 256, 0, stream>>>(high, he_dw_w, y1);
  k_gn<1, false><<<256, 512, 0, stream>>>(y1, nullptr, y1, he_gn1_g, he_gn1_b,
                                          nullptr, 0.f, 12, 1024, 10);
  k_conv1x1<384, 2><<<dim3(2, 24, 8), 256, 0, stream>>>(y1, he_pw_w, pw, 384, 1024);
  k_gn<0, true><<<256, 512, 0, stream>>>(pw, high, pw, he_gn2_g, he_gn2_b,
                                         alpha, 0.f, 12, 1024, 10);
  // 6) IWT + residual -> out
  k_iwt<<<4096, 256, 0, stream>>>(x, proj, pw, out);
  // 7) FFN
  k_conv1x1<128, 4><<<dim3(4, 16, 8), 256, 0, stream>>>(out, ffn_w1, f1, 256, 4096);
  k_gn<2, false><<<256, 512, 0, stream>>>(f1, nullptr, f1, ffn_gn1_g, ffn_gn1_b,
                                          nullptr, 0.f, 8, 4096, 12);
  k_conv1x1<256, 2><<<dim3(8, 8, 8), 256, 0, stream>>>(f1, ffn_w2, f3, 128, 4096);
  k_gn<0, true><<<256, 512, 0, stream>>>(f3, out, out, ffn_gn2_g, ffn_gn2_b,
                                         nullptr, 0.1f, 4, 4096, 12);
  (void)in_sizes; (void)n_in; (void)out_size; (void)ws_size;
}